// Round 7
// baseline (434.461 us; speedup 1.0000x reference)
//
#include <hip/hip_runtime.h>

// B=16, L=2048, K=24, D=64
typedef _Float16 f16;
typedef _Float16 f16x4 __attribute__((ext_vector_type(4)));
typedef _Float16 f16x8 __attribute__((ext_vector_type(8)));
typedef float f32x4 __attribute__((ext_vector_type(4)));

__device__ __forceinline__ void gl_lds16(const void* g, void* l) {
  __builtin_amdgcn_global_load_lds(
      (__attribute__((address_space(1))) unsigned int*)(g),
      (__attribute__((address_space(3))) unsigned int*)(l), 16, 0, 0);
}

// ---- k_pre: fused precompute.
// blocks 0..383:   Apre[diag][k][t][s] = lam_k^(1/4) * evec[diag*128+t-s][k]
// blocks 384..407: phiT[k][e][d] = (f16) m_phi[(k*64+d)*64 + e]
__global__ void k_pre(const float* __restrict__ m_phi, const float* __restrict__ ev,
                      const float* __restrict__ evec, f16* __restrict__ phiT,
                      f16* __restrict__ Apre) {
  int blk = blockIdx.x;
  if (blk < 384) {
    int diag = blk / 24, k = blk % 24;
    float s4 = sqrtf(sqrtf(ev[k]));
    f16* plane = Apre + (size_t)(diag * 24 + k) * 16384;
    for (int idx = threadIdx.x; idx < 16384; idx += 256) {
      int t = idx >> 7, s = idx & 127;
      int v = diag * 128 + t - s;
      float val = (v >= 0) ? evec[v * 24 + k] * s4 : 0.0f;
      plane[idx] = (f16)val;
    }
  } else {
    int k = blk - 384;
    for (int idx = threadIdx.x; idx < 4096; idx += 256) {
      int e = idx >> 6, d = idx & 63;
      phiT[k * 4096 + idx] = (f16)m_phi[(k * 64 + d) * 64 + e];
    }
  }
}

// ---- k_w: W2T[b][k][e][s] = sum_d in[b][s][d] * m_phi[k*64+d][e]   (f16 out)
// grid (16 s-tiles, 16 b, 4 k-groups of 6). [round-4 version — measured best:
// one-k-per-block variant regressed ~11us on redundant U loads + launch count]
__global__ __launch_bounds__(256) void k_w(const float* __restrict__ in,
                                           const f16* __restrict__ phiT,
                                           f16* __restrict__ W2T) {
  // Ubuf: U-fragments phase needs 128*64=8192; C-transpose phase needs 64*130=8320.
  __shared__ __align__(16) f16 Ubuf[8320];
  __shared__ __align__(16) f16 Psm[64 * 64];
  int s0 = blockIdx.x * 128;
  int b = blockIdx.y;
  int kg = blockIdx.z;
  int tid = threadIdx.x, lane = tid & 63, wv = tid >> 6;
  // stage U: fp32 -> f16, XOR-swizzled chunks (chunk = 16B = 8 elems)
#pragma unroll
  for (int v = 0; v < 4; ++v) {
    int flat = v * 256 + tid;
    int row = flat >> 3, cl = flat & 7, cg = cl ^ (row & 7);
    const float* g = in + ((size_t)(b * 2048 + s0 + row)) * 64 + cg * 8;
    float4 u0 = *(const float4*)g;
    float4 u1 = *(const float4*)(g + 4);
    f16x8 h;
    h[0] = (f16)u0.x; h[1] = (f16)u0.y; h[2] = (f16)u0.z; h[3] = (f16)u0.w;
    h[4] = (f16)u1.x; h[5] = (f16)u1.y; h[6] = (f16)u1.z; h[7] = (f16)u1.w;
    *(f16x8*)&Ubuf[row * 64 + cl * 8] = h;
  }
  __syncthreads();
  int wm = wv * 32;  // wave's 32 sigma rows
  // hoist A fragments (same for every k); Ubuf row area stays valid (transpose
  // only touches Ubuf after the barrier below each iteration)
  f16x8 af[2][2];
#pragma unroll
  for (int ks = 0; ks < 2; ++ks)
#pragma unroll
    for (int x = 0; x < 2; ++x) {
      int m = wm + x * 16 + (lane & 15);
      int ch = (ks * 4 + (lane >> 4)) ^ (m & 7);
      af[ks][x] = *(const f16x8*)&Ubuf[m * 64 + ch * 8];
    }
  for (int ki = 0; ki < 6; ++ki) {
    int k = kg * 6 + ki;
#pragma unroll
    for (int v = 0; v < 2; ++v) {
      int flat = v * 256 + tid;
      int row = flat >> 3, cl = flat & 7, cg = cl ^ (row & 7);
      gl_lds16(phiT + (size_t)k * 4096 + row * 64 + cg * 8,
               &Psm[(v * 256 + wv * 64) * 8]);
    }
    __syncthreads();  // Psm ready; prev iter's Csm reads all done
    f32x4 zero = {0.f, 0.f, 0.f, 0.f};
    f32x4 acc[2][4];
#pragma unroll
    for (int x = 0; x < 2; ++x)
#pragma unroll
      for (int y = 0; y < 4; ++y) acc[x][y] = zero;
#pragma unroll
    for (int ks = 0; ks < 2; ++ks) {
      f16x8 bf[4];
#pragma unroll
      for (int y = 0; y < 4; ++y) {
        int n = y * 16 + (lane & 15);
        int ch = (ks * 4 + (lane >> 4)) ^ (n & 7);
        bf[y] = *(const f16x8*)&Psm[n * 64 + ch * 8];
      }
#pragma unroll
      for (int x = 0; x < 2; ++x)
#pragma unroll
        for (int y = 0; y < 4; ++y)
          acc[x][y] = __builtin_amdgcn_mfma_f32_16x16x32_f16(af[ks][x], bf[y], acc[x][y], 0, 0, 0);
    }
    // transpose C (128 sigma x 64 e) into Ubuf[8320-area] as Csm[e][sigma], stride 130
#pragma unroll
    for (int x = 0; x < 2; ++x)
#pragma unroll
      for (int y = 0; y < 4; ++y) {
        int e = y * 16 + (lane & 15);
        int sg = wm + x * 16 + ((lane >> 4) << 2);
        f16x4 pk;
        pk[0] = (f16)acc[x][y][0]; pk[1] = (f16)acc[x][y][1];
        pk[2] = (f16)acc[x][y][2]; pk[3] = (f16)acc[x][y][3];
        *(f16x4*)&Ubuf[e * 130 + sg] = pk;
      }
    __syncthreads();  // Csm complete
    // coalesced stores: 1024 chunks of 16B; 16 lanes cover 256B of one e-row
#pragma unroll
    for (int pass = 0; pass < 4; ++pass) {
      int g = pass * 256 + tid;
      int e = g >> 4, ch = g & 15;
      f16x8 val = *(const f16x8*)&Ubuf[e * 130 + ch * 8];
      *(f16x8*)&W2T[((size_t)((b * 24 + k) * 64 + e)) * 2048 + s0 + ch * 8] = val;
    }
  }
}

// ---- k_main: causal block-Toeplitz GEMM, 128x128 tiles, diag-major grid.
// LDS-traffic-bound fix (round-6 model: 96KB LDS/blk-iter = 1129cyc vs 155cyc
// MFMA): A (Toeplitz) fragments are 16B-contiguous per lane, so A is read
// DIRECTLY from global (L2/L3-hot 12.6MB Apre; per-iter 16KB slice fits L1) --
// no A staging, no A LDS reads. B keeps round-4's wave-uniform gl_lds16 path.
// LDS/blk-iter: 96KB -> 48KB. (256,4): ~55 VGPR + 64 acc <= 128/wave target.
__global__ __launch_bounds__(256, 4) void k_main(const f16* __restrict__ Apre,
                                                 const f16* __restrict__ W2T,
                                                 float* __restrict__ out) {
  __shared__ __align__(16) f16 Bsm[128 * 64];  // 16 KB
  int nt = blockIdx.x;
  int q = blockIdx.y;
  int diag = 0, off = 0;
  while (off + (16 - diag) <= q) { off += 16 - diag; ++diag; }
  int st = q - off;
  int mt = st + diag;
  int tid = threadIdx.x, lane = tid & 63, wv = tid >> 6;
  int wm = (wv & 1) * 64, wn = (wv >> 1) * 64;
  int b0 = nt * 2;
  int ml = lane & 15, qv = lane >> 4;

  f32x4 zero = {0.f, 0.f, 0.f, 0.f};
  f32x4 acc[4][4];
#pragma unroll
  for (int x = 0; x < 4; ++x)
#pragma unroll
    for (int y = 0; y < 4; ++y) acc[x][y] = zero;

  const f16* aplane = Apre + (size_t)diag * 24 * 16384;
  // invariant per-lane A row offsets (elements): row (wm+x*16+ml), chunk qv
  int rowoff[4];
#pragma unroll
  for (int x = 0; x < 4; ++x) rowoff[x] = (wm + x * 16 + ml) * 128 + qv * 8;

  for (int i = 0; i < 48; ++i) {
    int k = i >> 1;
    int sh = (i & 1) << 6;  // which 64-s half of the s-tile
    const f16* ak = aplane + k * 16384 + sh;
#pragma unroll
    for (int v = 0; v < 4; ++v) {  // B tile: 128 n-rows x 64 s (16 KB)
      int flat = v * 256 + tid;
      int row = flat >> 3, cl = flat & 7, cg = cl ^ (row & 7);
      int bb = b0 + (row >> 6), e = row & 63;
      gl_lds16(W2T + ((size_t)((bb * 24 + k) * 64 + e)) * 2048 + st * 128 + sh + cg * 8,
               &Bsm[(v * 256 + wv * 64) * 8]);
    }
    __syncthreads();
#pragma unroll
    for (int ks = 0; ks < 2; ++ks) {
      f16x8 af[4], bf[4];
#pragma unroll
      for (int x = 0; x < 4; ++x)
        af[x] = *(const f16x8*)(ak + rowoff[x] + ks * 32);
#pragma unroll
      for (int y = 0; y < 4; ++y) {
        int n = wn + y * 16 + ml;
        int ch = (ks * 4 + qv) ^ (n & 7);
        bf[y] = *(const f16x8*)&Bsm[n * 64 + ch * 8];
      }
#pragma unroll
      for (int x = 0; x < 4; ++x)
#pragma unroll
        for (int y = 0; y < 4; ++y)
          acc[x][y] = __builtin_amdgcn_mfma_f32_16x16x32_f16(af[x], bf[y], acc[x][y], 0, 0, 0);
    }
    __syncthreads();
  }
  int t0 = mt * 128 + wm;
  int n0 = nt * 128 + wn;
#pragma unroll
  for (int x = 0; x < 4; ++x) {
    int rbase = t0 + x * 16 + (qv << 2);
#pragma unroll
    for (int y = 0; y < 4; ++y) {
      int col = n0 + y * 16 + ml;
      int b = col >> 6, e = col & 63;
#pragma unroll
      for (int r = 0; r < 4; ++r)
        atomicAdd(&out[((size_t)(b * 2048 + rbase + r)) * 64 + e], acc[x][y][r]);
    }
  }
}

extern "C" void kernel_launch(void* const* d_in, const int* in_sizes, int n_in,
                              void* d_out, int out_size, void* d_ws, size_t ws_size,
                              hipStream_t stream) {
  const float* inputs = (const float*)d_in[0];  // [16,2048,64]
  const float* m_phi = (const float*)d_in[1];   // [1536,64]
  const float* ev = (const float*)d_in[2];      // [24]
  const float* evec = (const float*)d_in[3];    // [2048,24]
  float* out = (float*)d_out;                   // [16,2048,64] fp32
  char* ws = (char*)d_ws;
  // ws layout: Apre 12,582,912 | phiT 196,608 | W2T 100,663,296
  f16* Apre = (f16*)(ws);
  f16* phiT = (f16*)(ws + 12582912);
  f16* W2T = (f16*)(ws + 12779520);

  hipMemsetAsync(out, 0, (size_t)out_size * 4, stream);
  hipLaunchKernelGGL(k_pre, dim3(408), dim3(256), 0, stream, m_phi, ev, evec, phiT, Apre);
  hipLaunchKernelGGL(k_w, dim3(16, 16, 4), dim3(256), 0, stream, inputs, phiT, W2T);
  hipLaunchKernelGGL(k_main, dim3(8, 136), dim3(256), 0, stream, Apre, W2T, out);
}

// Round 8
// 254.139 us; speedup vs baseline: 1.7095x; 1.7095x over previous
//
#include <hip/hip_runtime.h>

// B=16, L=2048, K=24, D=64
typedef _Float16 f16;
typedef _Float16 f16x4 __attribute__((ext_vector_type(4)));
typedef _Float16 f16x8 __attribute__((ext_vector_type(8)));
typedef float f32x4 __attribute__((ext_vector_type(4)));

__device__ __forceinline__ void gl_lds16(const void* g, void* l) {
  __builtin_amdgcn_global_load_lds(
      (__attribute__((address_space(1))) unsigned int*)(g),
      (__attribute__((address_space(3))) unsigned int*)(l), 16, 0, 0);
}

// ---- k_pre: fused precompute.
// blocks 0..383:   Apre[diag][k][t][s] = lam_k^(1/4) * evec[diag*128+t-s][k]
// blocks 384..407: phiT[k][e][d] = (f16) m_phi[(k*64+d)*64 + e]
__global__ void k_pre(const float* __restrict__ m_phi, const float* __restrict__ ev,
                      const float* __restrict__ evec, f16* __restrict__ phiT,
                      f16* __restrict__ Apre) {
  int blk = blockIdx.x;
  if (blk < 384) {
    int diag = blk / 24, k = blk % 24;
    float s4 = sqrtf(sqrtf(ev[k]));
    f16* plane = Apre + (size_t)(diag * 24 + k) * 16384;
    for (int idx = threadIdx.x; idx < 16384; idx += 256) {
      int t = idx >> 7, s = idx & 127;
      int v = diag * 128 + t - s;
      float val = (v >= 0) ? evec[v * 24 + k] * s4 : 0.0f;
      plane[idx] = (f16)val;
    }
  } else {
    int k = blk - 384;
    for (int idx = threadIdx.x; idx < 4096; idx += 256) {
      int e = idx >> 6, d = idx & 63;
      phiT[k * 4096 + idx] = (f16)m_phi[(k * 64 + d) * 64 + e];
    }
  }
}

// ---- k_w: W2T[b][k][e][s] = sum_d in[b][s][d] * m_phi[k*64+d][e]   (f16 out)
// grid (16 s-tiles, 16 b, 6 k-groups of 4) -> 1536 blocks, 6 blocks/CU
// (LDS 24.6KB/block): more resident blocks to overlap the per-iter 16KB
// store drains that vmcnt(0)-before-barrier forces.
__global__ __launch_bounds__(256) void k_w(const float* __restrict__ in,
                                           const f16* __restrict__ phiT,
                                           f16* __restrict__ W2T) {
  // Ubuf: U-fragments phase needs 128*64=8192; C-transpose phase needs 64*130=8320.
  __shared__ __align__(16) f16 Ubuf[8320];
  __shared__ __align__(16) f16 Psm[64 * 64];
  int s0 = blockIdx.x * 128;
  int b = blockIdx.y;
  int kg = blockIdx.z;
  int tid = threadIdx.x, lane = tid & 63, wv = tid >> 6;
  // stage U: fp32 -> f16, XOR-swizzled chunks (chunk = 16B = 8 elems)
#pragma unroll
  for (int v = 0; v < 4; ++v) {
    int flat = v * 256 + tid;
    int row = flat >> 3, cl = flat & 7, cg = cl ^ (row & 7);
    const float* g = in + ((size_t)(b * 2048 + s0 + row)) * 64 + cg * 8;
    float4 u0 = *(const float4*)g;
    float4 u1 = *(const float4*)(g + 4);
    f16x8 h;
    h[0] = (f16)u0.x; h[1] = (f16)u0.y; h[2] = (f16)u0.z; h[3] = (f16)u0.w;
    h[4] = (f16)u1.x; h[5] = (f16)u1.y; h[6] = (f16)u1.z; h[7] = (f16)u1.w;
    *(f16x8*)&Ubuf[row * 64 + cl * 8] = h;
  }
  __syncthreads();
  int wm = wv * 32;  // wave's 32 sigma rows
  // hoist A fragments (same for every k)
  f16x8 af[2][2];
#pragma unroll
  for (int ks = 0; ks < 2; ++ks)
#pragma unroll
    for (int x = 0; x < 2; ++x) {
      int m = wm + x * 16 + (lane & 15);
      int ch = (ks * 4 + (lane >> 4)) ^ (m & 7);
      af[ks][x] = *(const f16x8*)&Ubuf[m * 64 + ch * 8];
    }
  for (int ki = 0; ki < 4; ++ki) {
    int k = kg * 4 + ki;
#pragma unroll
    for (int v = 0; v < 2; ++v) {
      int flat = v * 256 + tid;
      int row = flat >> 3, cl = flat & 7, cg = cl ^ (row & 7);
      gl_lds16(phiT + (size_t)k * 4096 + row * 64 + cg * 8,
               &Psm[(v * 256 + wv * 64) * 8]);
    }
    __syncthreads();  // Psm ready; prev iter's Csm reads all done
    f32x4 zero = {0.f, 0.f, 0.f, 0.f};
    f32x4 acc[2][4];
#pragma unroll
    for (int x = 0; x < 2; ++x)
#pragma unroll
      for (int y = 0; y < 4; ++y) acc[x][y] = zero;
#pragma unroll
    for (int ks = 0; ks < 2; ++ks) {
      f16x8 bf[4];
#pragma unroll
      for (int y = 0; y < 4; ++y) {
        int n = y * 16 + (lane & 15);
        int ch = (ks * 4 + (lane >> 4)) ^ (n & 7);
        bf[y] = *(const f16x8*)&Psm[n * 64 + ch * 8];
      }
#pragma unroll
      for (int x = 0; x < 2; ++x)
#pragma unroll
        for (int y = 0; y < 4; ++y)
          acc[x][y] = __builtin_amdgcn_mfma_f32_16x16x32_f16(af[ks][x], bf[y], acc[x][y], 0, 0, 0);
    }
    // transpose C (128 sigma x 64 e) into Ubuf as Csm[e][sigma], stride 130
#pragma unroll
    for (int x = 0; x < 2; ++x)
#pragma unroll
      for (int y = 0; y < 4; ++y) {
        int e = y * 16 + (lane & 15);
        int sg = wm + x * 16 + ((lane >> 4) << 2);
        f16x4 pk;
        pk[0] = (f16)acc[x][y][0]; pk[1] = (f16)acc[x][y][1];
        pk[2] = (f16)acc[x][y][2]; pk[3] = (f16)acc[x][y][3];
        *(f16x4*)&Ubuf[e * 130 + sg] = pk;
      }
    __syncthreads();  // Csm complete
    // coalesced stores: 1024 chunks of 16B; 16 lanes cover 256B of one e-row
#pragma unroll
    for (int pass = 0; pass < 4; ++pass) {
      int g = pass * 256 + tid;
      int e = g >> 4, ch = g & 15;
      f16x8 val = *(const f16x8*)&Ubuf[e * 130 + ch * 8];
      *(f16x8*)&W2T[((size_t)((b * 24 + k) * 64 + e)) * 2048 + s0 + ch * 8] = val;
    }
  }
}

// ---- k_main: causal block-Toeplitz GEMM, 128x128 tiles, split-K over s-tiles
// with fp32 atomicAdd epilogue directly into out[b][t][e].
// grid = (nt 0..7, q 0..135) with q DIAG-MAJOR: same-diag blocks adjacent
// (A-plane L2 reuse), same-out-tile blocks spread (atomic contention spread).
// [exact round-4 version — 157us. Verified local optimum: 128x256 (R2),
//  z-split (R3), A-direct-global (R5/R7) all regressed.]
__global__ __launch_bounds__(256, 2) void k_main(const f16* __restrict__ Apre,
                                                 const f16* __restrict__ W2T,
                                                 float* __restrict__ out) {
  __shared__ __align__(16) f16 Asm[128 * 64];
  __shared__ __align__(16) f16 Bsm[128 * 64];
  int nt = blockIdx.x;
  int q = blockIdx.y;
  int diag = 0, off = 0;
  while (off + (16 - diag) <= q) { off += 16 - diag; ++diag; }
  int st = q - off;
  int mt = st + diag;
  int tid = threadIdx.x, lane = tid & 63, wv = tid >> 6;
  int wm = (wv & 1) * 64, wn = (wv >> 1) * 64;
  int b0 = nt * 2;

  f32x4 zero = {0.f, 0.f, 0.f, 0.f};
  f32x4 acc[4][4];
#pragma unroll
  for (int x = 0; x < 4; ++x)
#pragma unroll
    for (int y = 0; y < 4; ++y) acc[x][y] = zero;

  const f16* aplane = Apre + (size_t)diag * 24 * 16384;

  for (int i = 0; i < 48; ++i) {
    int k = i >> 1;
    int sh = (i & 1) << 6;  // which 64-s half of the s-tile
    const f16* ak = aplane + k * 16384;
#pragma unroll
    for (int v = 0; v < 4; ++v) {  // A tile: 128 t-rows x 64 s (16 KB)
      int flat = v * 256 + tid;
      int row = flat >> 3, cl = flat & 7, cg = cl ^ (row & 7);
      gl_lds16(ak + row * 128 + sh + cg * 8, &Asm[(v * 256 + wv * 64) * 8]);
    }
#pragma unroll
    for (int v = 0; v < 4; ++v) {  // B tile: 128 n-rows x 64 s (16 KB)
      int flat = v * 256 + tid;
      int row = flat >> 3, cl = flat & 7, cg = cl ^ (row & 7);
      int bb = b0 + (row >> 6), e = row & 63;
      gl_lds16(W2T + ((size_t)((bb * 24 + k) * 64 + e)) * 2048 + st * 128 + sh + cg * 8,
               &Bsm[(v * 256 + wv * 64) * 8]);
    }
    __syncthreads();
#pragma unroll
    for (int ks = 0; ks < 2; ++ks) {
      f16x8 af[4], bf[4];
#pragma unroll
      for (int x = 0; x < 4; ++x) {
        int m = wm + x * 16 + (lane & 15);
        int ch = (ks * 4 + (lane >> 4)) ^ (m & 7);
        af[x] = *(const f16x8*)&Asm[m * 64 + ch * 8];
      }
#pragma unroll
      for (int y = 0; y < 4; ++y) {
        int n = wn + y * 16 + (lane & 15);
        int ch = (ks * 4 + (lane >> 4)) ^ (n & 7);
        bf[y] = *(const f16x8*)&Bsm[n * 64 + ch * 8];
      }
#pragma unroll
      for (int x = 0; x < 4; ++x)
#pragma unroll
        for (int y = 0; y < 4; ++y)
          acc[x][y] = __builtin_amdgcn_mfma_f32_16x16x32_f16(af[x], bf[y], acc[x][y], 0, 0, 0);
    }
    __syncthreads();
  }
  int t0 = mt * 128 + wm;
  int n0 = nt * 128 + wn;
#pragma unroll
  for (int x = 0; x < 4; ++x) {
    int rbase = t0 + x * 16 + ((lane >> 4) << 2);
#pragma unroll
    for (int y = 0; y < 4; ++y) {
      int col = n0 + y * 16 + (lane & 15);
      int b = col >> 6, e = col & 63;
#pragma unroll
      for (int r = 0; r < 4; ++r)
        atomicAdd(&out[((size_t)(b * 2048 + rbase + r)) * 64 + e], acc[x][y][r]);
    }
  }
}

extern "C" void kernel_launch(void* const* d_in, const int* in_sizes, int n_in,
                              void* d_out, int out_size, void* d_ws, size_t ws_size,
                              hipStream_t stream) {
  const float* inputs = (const float*)d_in[0];  // [16,2048,64]
  const float* m_phi = (const float*)d_in[1];   // [1536,64]
  const float* ev = (const float*)d_in[2];      // [24]
  const float* evec = (const float*)d_in[3];    // [2048,24]
  float* out = (float*)d_out;                   // [16,2048,64] fp32
  char* ws = (char*)d_ws;
  // ws layout: Apre 12,582,912 | phiT 196,608 | W2T 100,663,296
  f16* Apre = (f16*)(ws);
  f16* phiT = (f16*)(ws + 12582912);
  f16* W2T = (f16*)(ws + 12779520);

  hipMemsetAsync(out, 0, (size_t)out_size * 4, stream);
  hipLaunchKernelGGL(k_pre, dim3(408), dim3(256), 0, stream, m_phi, ev, evec, phiT, Apre);
  hipLaunchKernelGGL(k_w, dim3(16, 16, 6), dim3(256), 0, stream, inputs, phiT, W2T);
  hipLaunchKernelGGL(k_main, dim3(8, 136), dim3(256), 0, stream, Apre, W2T, out);
}